// Round 11
// baseline (276.174 us; speedup 1.0000x reference)
//
#include <hip/hip_runtime.h>
#include <string.h>

// Exact k-th order statistic + mask, fp32, n = 64*1024*1024.
// Two proven-shape streaming passes, NO candidate compaction:
//   k1 hist20B1 : read x, chi tally, rare global-atomic 20-bit hist of bin B1
//   reduce/flagveri/scan20B : exact verification + threshold -> st[9] (float bits)
//   k2 mask_kernel : float4 read, x >= thr, plain store (r1's proven kernel)
//   fallback : proven 3-pass radix select, always enqueued, flag-gated -> st[9]
//
// state: [2]=chi [3]=flag [4]=r' [5]=chunk [6]=rA [9]=thr float bits
//        [10..15]=fb chain
//
// ws ints: ST(32) | H20(1M) | FB1(4096) | FB2(4096) | FB3(256)  <- zeroed
//          | PART(1024)

#define N_STATE  32
#define H20_OFF  32
#define FB1_OFF  (H20_OFF + 1048576)
#define FB2_OFF  (FB1_OFF + 4096)
#define FB3_OFF  (FB2_OFF + 4096)
#define FIXED_Z  (FB3_OFF + 256)          // zeroed every call (~4.23 MB)
#define PART_OFF FIXED_Z

#define FB_WS_INTS (16 + 4096 + 4096 + 256)

__device__ __forceinline__ unsigned map_bits(unsigned raw) {
    return (raw & 0x80000000u) ? ~raw : (raw | 0x80000000u);
}

// ---------------- workspace zeroing ----------------
__global__ void __launch_bounds__(256)
zero_ws(uint4* __restrict__ p, int n16)
{
    int i = blockIdx.x * 256 + threadIdx.x;
    int s = gridDim.x * 256;
    uint4 z = make_uint4(0u, 0u, 0u, 0u);
    for (; i < n16; i += s) p[i] = z;
}

// ---------------- k1: hist of bin B1 (r1 hist-pass shape) ----------------
__global__ void __launch_bounds__(256)
hist20B1(const uint4* __restrict__ x, int n4, unsigned* __restrict__ h20,
         unsigned* __restrict__ st, unsigned B1)
{
    const unsigned lane = threadIdx.x & 63u;
    unsigned chi = 0;
    int idx = blockIdx.x * blockDim.x + threadIdx.x;
    int stride = gridDim.x * blockDim.x;
    for (int i = idx; i < n4; i += stride) {
        uint4 v = x[i];
        unsigned u, p;
        u = map_bits(v.x); p = u >> 20; chi += (p > B1) ? 1u : 0u;
        if (p == B1) atomicAdd(&h20[u & 0xFFFFFu], 1u);
        u = map_bits(v.y); p = u >> 20; chi += (p > B1) ? 1u : 0u;
        if (p == B1) atomicAdd(&h20[u & 0xFFFFFu], 1u);
        u = map_bits(v.z); p = u >> 20; chi += (p > B1) ? 1u : 0u;
        if (p == B1) atomicAdd(&h20[u & 0xFFFFFu], 1u);
        u = map_bits(v.w); p = u >> 20; chi += (p > B1) ? 1u : 0u;
        if (p == B1) atomicAdd(&h20[u & 0xFFFFFu], 1u);
    }
    for (int off = 32; off > 0; off >>= 1) chi += __shfl_down(chi, off, 64);
    if (lane == 0) atomicAdd(&st[2], chi);
}

// ---------------- chunk reduction (ungated) ----------------
__global__ void __launch_bounds__(256)
reduce_chunks(const unsigned* __restrict__ h20, unsigned* __restrict__ part)
{
    __shared__ unsigned s[256];
    unsigned sum = 0;
    int base = blockIdx.x * 1024;
    for (int t = threadIdx.x; t < 1024; t += 256) sum += h20[base + t];
    s[threadIdx.x] = sum;
    __syncthreads();
    for (int off = 128; off > 0; off >>= 1) {
        if (threadIdx.x < off) s[threadIdx.x] += s[threadIdx.x + off];
        __syncthreads();
    }
    if (threadIdx.x == 0) part[blockIdx.x] = s[0];
}

// ---------------- exact verification + level-A chunk select ----------------
__global__ void __launch_bounds__(1024)
flagveri(const unsigned* __restrict__ part, unsigned n, unsigned r,
         unsigned* __restrict__ st)
{
    __shared__ unsigned s[1024];
    __shared__ unsigned sh_r2;
    int t = threadIdx.x;
    unsigned v = part[t];
    s[t] = v;
    __syncthreads();
    for (int off = 1; off < 1024; off <<= 1) {
        unsigned w = (t >= off) ? s[t - off] : 0u;
        __syncthreads();
        s[t] += w;
        __syncthreads();
    }
    unsigned Nc = s[1023];
    if (t == 0) {
        unsigned long long chi = st[2];
        unsigned long long Nlt_lo = (unsigned long long)n - chi - (unsigned long long)Nc;
        unsigned flag = 0;
        if (!((Nlt_lo <= (unsigned long long)r) &&
              ((unsigned long long)r < Nlt_lo + (unsigned long long)Nc))) flag = 1;
        st[3] = flag;
        unsigned r2 = (unsigned)((unsigned long long)r - Nlt_lo);
        st[4] = r2;
        sh_r2 = r2;
    }
    __syncthreads();
    unsigned rank = sh_r2;
    unsigned incl = s[t], excl = incl - v;
    if (rank >= excl && rank < incl) { st[5] = (unsigned)t; st[6] = rank - excl; }
}

// ---------------- level-B bin select -> float threshold bits (gated) -------
__global__ void __launch_bounds__(1024)
scan20B(const unsigned* __restrict__ h20, unsigned* __restrict__ st, unsigned B1)
{
    if (st[3] != 0u) return;
    __shared__ unsigned s[1024];
    int t = threadIdx.x;
    unsigned chunk = st[5];
    unsigned rank = st[6];
    unsigned v = h20[(size_t)chunk * 1024 + t];
    s[t] = v;
    __syncthreads();
    for (int off = 1; off < 1024; off <<= 1) {
        unsigned w = (t >= off) ? s[t - off] : 0u;
        __syncthreads();
        s[t] += w;
        __syncthreads();
    }
    unsigned incl = s[t], excl = incl - v;
    if (rank >= excl && rank < incl) {
        unsigned u = (B1 << 20) | (chunk << 10) | (unsigned)t;
        st[9] = (u & 0x80000000u) ? (u & 0x7FFFFFFFu) : ~u;   // inverse map
    }
}

// ---------------- fallback (proven 3-pass radix), flag-gated ----------------
__global__ void __launch_bounds__(256)
hist_pass(const uint4* __restrict__ x, int n4, int shift, int nbins, int mode,
          const unsigned* __restrict__ state, unsigned* __restrict__ hist,
          const unsigned* __restrict__ gate)
{
    if (gate && *gate == 0u) return;
    __shared__ unsigned lh[4096];
    for (int i = threadIdx.x; i < nbins; i += blockDim.x) lh[i] = 0u;
    __syncthreads();

    unsigned tgt = 0; int mshift = 0;
    if (mode == 1)      { tgt = state[0];                      mshift = 20; }
    else if (mode == 2) { tgt = (state[0] << 12) | state[2];   mshift = 8;  }

    const unsigned binmask = (unsigned)(nbins - 1);
    int idx = blockIdx.x * blockDim.x + threadIdx.x;
    int stride = gridDim.x * blockDim.x;
    for (int i = idx; i < n4; i += stride) {
        uint4 v = x[i];
        unsigned u;
        u = map_bits(v.x); if (!mode || (u >> mshift) == tgt) atomicAdd(&lh[(u >> shift) & binmask], 1u);
        u = map_bits(v.y); if (!mode || (u >> mshift) == tgt) atomicAdd(&lh[(u >> shift) & binmask], 1u);
        u = map_bits(v.z); if (!mode || (u >> mshift) == tgt) atomicAdd(&lh[(u >> shift) & binmask], 1u);
        u = map_bits(v.w); if (!mode || (u >> mshift) == tgt) atomicAdd(&lh[(u >> shift) & binmask], 1u);
    }
    __syncthreads();
    for (int i = threadIdx.x; i < nbins; i += blockDim.x) {
        unsigned c = lh[i];
        if (c) atomicAdd(&hist[i], c);
    }
}

__global__ void __launch_bounds__(1024)
scan_select(const unsigned* __restrict__ hist, int nbins,
            const unsigned* __restrict__ rank_in, unsigned rank_imm,
            unsigned* __restrict__ bin_out, unsigned* __restrict__ rank_out,
            const unsigned* __restrict__ gate, int want_nonzero)
{
    if (gate) {
        unsigned g = *gate;
        if ((g != 0u) != (want_nonzero != 0)) return;
    }
    __shared__ unsigned s[1024];
    int t = threadIdx.x;
    unsigned rank = rank_in ? *rank_in : rank_imm;
    int per = (nbins + 1023) >> 10;
    int base = t * per;
    unsigned mySum = 0;
    for (int i = 0; i < per; ++i) {
        int b = base + i;
        if (b < nbins) mySum += hist[b];
    }
    s[t] = mySum;
    __syncthreads();
    for (int off = 1; off < 1024; off <<= 1) {
        unsigned v = (t >= off) ? s[t - off] : 0u;
        __syncthreads();
        s[t] += v;
        __syncthreads();
    }
    unsigned incl = s[t];
    unsigned excl = incl - mySum;
    if (rank >= excl && rank < incl) {
        unsigned run = excl;
        for (int i = 0; i < per; ++i) {
            int b = base + i;
            unsigned c = (b < nbins) ? hist[b] : 0u;
            if (rank < run + c) { *bin_out = (unsigned)b; *rank_out = rank - run; break; }
            run += c;
        }
    }
}

__global__ void finalize_thr_fb(unsigned* st, const unsigned* gate) {
    if (gate && *gate == 0u) return;
    unsigned u = (st[10] << 20) | (st[12] << 8) | st[14];
    st[9] = (u & 0x80000000u) ? (u & 0x7FFFFFFFu) : ~u;
}

// ---------------- k2: final mask (r1's proven kernel, ungated) ----------------
__global__ void __launch_bounds__(256)
mask_kernel(const float4* __restrict__ x, float4* __restrict__ out, int n4,
            const unsigned* __restrict__ st)
{
    float thr = __uint_as_float(st[9]);
    int idx = blockIdx.x * blockDim.x + threadIdx.x;
    int stride = gridDim.x * blockDim.x;
    for (int i = idx; i < n4; i += stride) {
        float4 v = x[i];
        float4 o;
        o.x = (v.x >= thr) ? 1.0f : 0.0f;
        o.y = (v.y >= thr) ? 1.0f : 0.0f;
        o.z = (v.z >= thr) ? 1.0f : 0.0f;
        o.w = (v.w >= thr) ? 1.0f : 0.0f;
        out[i] = o;
    }
}

__global__ void __launch_bounds__(256)
mask_kernel_fb(const float4* __restrict__ x, float4* __restrict__ out, int n4,
               const unsigned* __restrict__ st)
{
    float thr = __uint_as_float(st[9]);
    int idx = blockIdx.x * blockDim.x + threadIdx.x;
    int stride = gridDim.x * blockDim.x;
    for (int i = idx; i < n4; i += stride) {
        float4 v = x[i];
        float4 o;
        o.x = (v.x >= thr) ? 1.0f : 0.0f;
        o.y = (v.y >= thr) ? 1.0f : 0.0f;
        o.z = (v.z >= thr) ? 1.0f : 0.0f;
        o.w = (v.w >= thr) ? 1.0f : 0.0f;
        out[i] = o;
    }
}

// ---------------- host ----------------
static inline unsigned host_map(float f) {
    unsigned raw; memcpy(&raw, &f, 4);
    return (raw & 0x80000000u) ? ~raw : (raw | 0x80000000u);
}

extern "C" void kernel_launch(void* const* d_in, const int* in_sizes, int n_in,
                              void* d_out, int out_size, void* d_ws, size_t ws_size,
                              hipStream_t stream)
{
    const float* x = (const float*)d_in[0];
    float* out = (float*)d_out;
    long long n = (long long)in_sizes[0];
    long long k = (long long)((double)n * 0.9);   // matches Python int(n * RATIO)

    if (k <= 0) {
        hipMemsetAsync(d_out, 0, (size_t)out_size * sizeof(float), stream);
        return;
    }

    unsigned* ws = (unsigned*)d_ws;
    unsigned* st = ws;
    int n4 = (int)(n / 4);
    const uint4* x4 = (const uint4*)x;
    unsigned r = (unsigned)(n - k);               // ascending rank of threshold

    size_t need_fast = (size_t)(PART_OFF + 1024) * 4;

    if (ws_size >= need_fast) {
        unsigned* h20  = ws + H20_OFF;
        unsigned* fb1  = ws + FB1_OFF;
        unsigned* fb2  = ws + FB2_OFF;
        unsigned* fb3  = ws + FB3_OFF;
        unsigned* part = ws + PART_OFF;

        // Static coarse bin: the 2^20-wide bin containing the 0.1-quantile of
        // N(0,1) (x in (-1.375, -1.25], mass 0.0846..0.1056 straddles 0.1).
        // Exactness does NOT depend on it: flag-verified, fallback-gated.
        unsigned B1 = host_map(-1.2816f) >> 20;

        zero_ws<<<512, 256, 0, stream>>>((uint4*)d_ws, FIXED_Z / 4);
        hist20B1<<<2048, 256, 0, stream>>>(x4, n4, h20, st, B1);
        reduce_chunks<<<1024, 256, 0, stream>>>(h20, part);
        flagveri<<<1, 1024, 0, stream>>>(part, (unsigned)n, r, st);
        scan20B<<<1, 1024, 0, stream>>>(h20, st, B1);
        // fallback chain (gated on flag!=0) — proven exact path, writes st[9]
        hist_pass<<<1024, 256, 0, stream>>>(x4, n4, 20, 4096, 0, &st[10], fb1, &st[3]);
        scan_select<<<1, 1024, 0, stream>>>(fb1, 4096, nullptr, r, &st[10], &st[11], &st[3], 1);
        hist_pass<<<1024, 256, 0, stream>>>(x4, n4, 8, 4096, 1, &st[10], fb2, &st[3]);
        scan_select<<<1, 1024, 0, stream>>>(fb2, 4096, &st[11], 0u, &st[12], &st[13], &st[3], 1);
        hist_pass<<<1024, 256, 0, stream>>>(x4, n4, 0, 256, 2, &st[10], fb3, &st[3]);
        scan_select<<<1, 1024, 0, stream>>>(fb3, 256, &st[13], 0u, &st[14], &st[15], &st[3], 1);
        finalize_thr_fb<<<1, 1, 0, stream>>>(st, &st[3]);
        // final mask for BOTH paths (st[9] written by exactly one of them)
        mask_kernel<<<2048, 256, 0, stream>>>((const float4*)x, (float4*)out, n4, st);
    } else {
        // small-ws standalone fallback: 3-pass radix + mask (ungated)
        unsigned* h1 = ws + 16;
        unsigned* h2 = ws + 16 + 4096;
        unsigned* h3 = ws + 16 + 8192;

        hipMemsetAsync(d_ws, 0, FB_WS_INTS * sizeof(unsigned), stream);

        hist_pass<<<2048, 256, 0, stream>>>(x4, n4, 20, 4096, 0, &ws[10], h1, nullptr);
        scan_select<<<1, 1024, 0, stream>>>(h1, 4096, nullptr, r, &ws[10], &ws[11], nullptr, 0);
        hist_pass<<<2048, 256, 0, stream>>>(x4, n4, 8, 4096, 1, &ws[10], h2, nullptr);
        scan_select<<<1, 1024, 0, stream>>>(h2, 4096, &ws[11], 0u, &ws[12], &ws[13], nullptr, 0);
        hist_pass<<<2048, 256, 0, stream>>>(x4, n4, 0, 256, 2, &ws[10], h3, nullptr);
        scan_select<<<1, 1024, 0, stream>>>(h3, 256, &ws[13], 0u, &ws[14], &ws[15], nullptr, 0);
        finalize_thr_fb<<<1, 1, 0, stream>>>(ws, nullptr);
        mask_kernel_fb<<<2048, 256, 0, stream>>>((const float4*)x, (float4*)out, n4, ws);
    }
}